// Round 6
// baseline (253.516 us; speedup 1.0000x reference)
//
#include <hip/hip_runtime.h>
#include <hip/hip_bf16.h>

// Problem constants
#define BSZ 4
#define LSEQ 2048
#define VECD 512
#define NH 8
#define HD 64

typedef __attribute__((ext_vector_type(8))) short bf16x8;
typedef __attribute__((ext_vector_type(4))) short short4v;
typedef __attribute__((ext_vector_type(8))) short short8v;
typedef __attribute__((ext_vector_type(4))) float f32x4;

__device__ inline short f2bf(float f) {
    union { float f; unsigned u; } v; v.f = f;
    unsigned u = v.u;
    u += 0x7fffu + ((u >> 16) & 1u);   // RNE
    return (short)(u >> 16);
}

__device__ inline void gll16(const void* g, void* l) {
    __builtin_amdgcn_global_load_lds(
        (const __attribute__((address_space(1))) unsigned int*)g,
        (__attribute__((address_space(3))) unsigned int*)l, 16, 0, 0);
}

// ---------------------------------------------------------------------------
// Kernel 0: W -> WT bf16 transpose.  WT[z][(h*64+d)*512 + k] = W_z[h][k][d]
// ---------------------------------------------------------------------------
__launch_bounds__(256)
__global__ void w_kernel(const float* __restrict__ Wq, const float* __restrict__ Wk,
                         const float* __restrict__ Wv, short* __restrict__ WT) {
    __shared__ short T[64][72];
    const int bi = blockIdx.x;
    const int z = bi >> 3, h = bi & 7;
    const float* W = ((z == 0) ? Wq : (z == 1) ? Wk : Wv) + (size_t)h * VECD * HD;
    short* out = WT + (size_t)z * 512 * 512 + (size_t)h * 64 * 512;

    const int tid = threadIdx.x;
    for (int kt = 0; kt < 8; kt++) {
        int k0 = kt * 64;
        int r = tid >> 2, seg = tid & 3;
        for (int j = 0; j < 4; j++) {
            float4 v = *(const float4*)(W + (size_t)(k0 + r) * HD + seg * 16 + j * 4);
            T[seg * 16 + j * 4 + 0][r] = f2bf(v.x);
            T[seg * 16 + j * 4 + 1][r] = f2bf(v.y);
            T[seg * 16 + j * 4 + 2][r] = f2bf(v.z);
            T[seg * 16 + j * 4 + 3][r] = f2bf(v.w);
        }
        __syncthreads();
        int d = tid >> 2, ks = tid & 3;
        *(short8v*)(out + (size_t)d * 512 + k0 + ks * 16) = *(const short8v*)&T[d][ks * 16];
        *(short8v*)(out + (size_t)d * 512 + k0 + ks * 16 + 8) = *(const short8v*)&T[d][ks * 16 + 8];
        __syncthreads();
    }
}

// ---------------------------------------------------------------------------
// Kernel 1: QKV projection GEMM (unchanged from round 5).
// ---------------------------------------------------------------------------
__launch_bounds__(256, 3)
__global__ void proj_kernel(const float* __restrict__ q_in, const float* __restrict__ k_in,
                            const float* __restrict__ v_in, const short* __restrict__ WT,
                            short* __restrict__ Qp, short* __restrict__ Kp,
                            short* __restrict__ Vp) {
    __shared__ short As[128 * 64];
    __shared__ short Bs[128 * 64];

    const int z = blockIdx.z;
    const float* in = (z == 0) ? q_in : (z == 1) ? k_in : v_in;
    short* out      = (z == 0) ? Qp   : (z == 1) ? Kp   : Vp;
    const float sc  = (z == 0) ? 0.125f : 1.0f;
    const short* wt = WT + (size_t)z * 512 * 512;

    const int tid  = threadIdx.x;
    const int lane = tid & 63;
    const int w    = tid >> 6;
    const int r0   = blockIdx.x * 128;
    const int n0   = blockIdx.y * 128;

    const int row16 = lane & 15;
    const int grp   = lane >> 4;
    const int wm    = (w >> 1) * 64;
    const int wn    = (w & 1) * 64;

    f32x4 acc[4][4];
    for (int i = 0; i < 4; i++)
        for (int j = 0; j < 4; j++) acc[i][j] = (f32x4)0.f;

    for (int k0 = 0; k0 < VECD; k0 += 64) {
        for (int i = 0; i < 8; i++) {
            int id = tid + 256 * i;
            int m = id >> 4, kc4 = id & 15;
            float4 v = *(const float4*)(in + (size_t)(r0 + m) * VECD + k0 + kc4 * 4);
            int c = kc4 >> 1, half = kc4 & 1;
            short4v s4;
            s4[0] = f2bf(v.x); s4[1] = f2bf(v.y); s4[2] = f2bf(v.z); s4[3] = f2bf(v.w);
            *(short4v*)&As[m * 64 + (c ^ (m & 7)) * 8 + half * 4] = s4;
        }
        for (int i = 0; i < 4; i++) {
            int id = tid + 256 * i;
            int n = id >> 3, c = id & 7;
            gll16(wt + (size_t)(n0 + n) * 512 + k0 + ((c ^ (n & 7)) * 8),
                  (void*)(Bs + (w * 64 + 256 * i) * 8));
        }
        __syncthreads();

        for (int kc = 0; kc < 2; kc++) {
            bf16x8 a[4], b[4];
            for (int mt = 0; mt < 4; mt++) {
                int row = wm + mt * 16 + row16;
                int cg = kc * 4 + grp;
                a[mt] = *(const bf16x8*)&As[row * 64 + (cg ^ (row & 7)) * 8];
            }
            for (int nt = 0; nt < 4; nt++) {
                int row = wn + nt * 16 + row16;
                int cg = kc * 4 + grp;
                b[nt] = *(const bf16x8*)&Bs[row * 64 + (cg ^ (row & 7)) * 8];
            }
            for (int mt = 0; mt < 4; mt++)
                for (int nt = 0; nt < 4; nt++)
                    acc[mt][nt] = __builtin_amdgcn_mfma_f32_16x16x32_bf16(a[mt], b[nt], acc[mt][nt], 0, 0, 0);
        }
        __syncthreads();
    }

    for (int mt = 0; mt < 4; mt++)
        for (int r = 0; r < 4; r++) {
            int m = r0 + wm + mt * 16 + grp * 4 + r;
            int b = m >> 11, l = m & (LSEQ - 1);
            for (int nt = 0; nt < 4; nt++) {
                int n = n0 + wn + nt * 16 + row16;
                int h = n >> 6, d = n & 63;
                out[(((size_t)b * NH + h) * LSEQ + l) * HD + d] = f2bf(acc[mt][nt][r] * sc);
            }
        }
}

// ---------------------------------------------------------------------------
// Kernel 2: attention, m-split in 2 halves (blockIdx.z) for 2x grid parallelism.
// Block z handles K-tiles [16z, 16z+16): PV tiles (k<=qi) via LDS + swizzle,
// denominator-only tiles direct from global with reg double-buffer.
// Writes UN-normalized partial o and partial denominator; LN kernel combines.
// grid = (32, 32, 2), block = 256 (4 waves, 16 q-rows each).
// ---------------------------------------------------------------------------
__launch_bounds__(256, 6)
__global__ void attn_kernel(const short* __restrict__ Qp, const short* __restrict__ Kp,
                            const short* __restrict__ Vp,
                            const float* __restrict__ vmask,
                            float* __restrict__ part_o, float* __restrict__ part_d) {
    __shared__ short Ks[64 * 64];       // [m][k-chunks], slot c holds chunk c^(m&7)
    __shared__ short VTs[64 * 64];      // [d][m], chunk' = (m>>3)^(d&7)^((d>>3)&7)
    __shared__ short Ps[4][16][72];     // per-wave P: [q][m]

    const int tid  = threadIdx.x;
    const int lane = tid & 63;
    const int w    = tid >> 6;
    const int bh   = blockIdx.y;
    const int b    = bh >> 3;
    const int h    = bh & 7;
    const int z    = blockIdx.z;
    const int klo  = z * 16, khi = klo + 16;
    // complementary-pair load-balance swizzle
    const int g    = (blockIdx.x + (bh & 15)) & 31;
    const int qi   = (bh & 16) ? (31 - g) : g;
    const int l0   = qi * 64;
    const int qbase = l0 + w * 16;
    const size_t base = (size_t)bh * LSEQ * HD;

    const int row16 = lane & 15;
    const int grp   = lane >> 4;
    const int rm7   = row16 & 7;
    const int r3    = row16 >> 3;

    bf16x8 q[2];
    for (int c = 0; c < 2; c++)
        q[c] = *(const bf16x8*)(Qp + base + (size_t)(qbase + row16) * HD + c * 32 + grp * 8);

    f32x4 o[4];
    for (int i = 0; i < 4; i++) o[i] = (f32x4)0.f;
    float dsum[4] = {0.f, 0.f, 0.f, 0.f};

    // ---------------- Phase A: PV tiles k in [klo, min(qi, khi-1)] ----------------
    const int kA_end = (qi < khi - 1) ? qi : (khi - 1);
    for (int k = klo; k <= kA_end; ++k) {
        const int m0 = k * 64;
        {
            const short* ksrc = Kp + base + (size_t)m0 * HD;
            for (int i = 0; i < 2; i++) {
                int id = tid + 256 * i;
                int m = id >> 3;
                int scnk = (id & 7) ^ (m & 7);
                gll16(ksrc + m * HD + scnk * 8, (void*)(Ks + (w * 64 + 256 * i) * 8));
            }
        }
        {
            const short* vsrc = Vp + base + (size_t)m0 * HD;
            for (int i = 0; i < 2; i++) {
                int id = tid + 256 * i;
                int m = id >> 3, c8 = id & 7;
                bf16x8 v = *(const bf16x8*)(vsrc + m * HD + c8 * 8);
                int mhi = m >> 3, mlo = m & 7;
                for (int j = 0; j < 8; j++) {
                    int d = c8 * 8 + j;
                    int ck = mhi ^ (d & 7) ^ ((d >> 3) & 7);
                    VTs[d * 64 + ck * 8 + mlo] = v[j];
                }
            }
        }
        __syncthreads();

        f32x4 s[4];
        for (int st = 0; st < 4; st++) s[st] = (f32x4)0.f;
        for (int c = 0; c < 2; c++) {
            int ck = ((c << 2) | grp) ^ rm7;
            for (int st = 0; st < 4; st++) {
                bf16x8 kf = *(const bf16x8*)&Ks[(st * 16 + row16) * 64 + ck * 8];
                s[st] = __builtin_amdgcn_mfma_f32_16x16x32_bf16(q[c], kf, s[st], 0, 0, 0);
            }
        }

        float e[4][4];
        for (int st = 0; st < 4; st++)
            for (int r = 0; r < 4; r++) {
                float ev = __expf(s[st][r]);
                e[st][r] = ev;
                dsum[r] += ev;
            }

        for (int st = 0; st < 4; st++) {
            int m = m0 + st * 16 + row16;
            float vm = vmask[b * LSEQ + m];
            for (int r = 0; r < 4; r++) {
                int lq = qbase + grp * 4 + r;
                float pv = (m <= lq) ? e[st][r] * vm : 0.f;
                Ps[w][grp * 4 + r][st * 16 + row16] = f2bf(pv);
            }
        }

        for (int c = 0; c < 2; c++) {
            int cg = (c << 2) | grp;
            bf16x8 pa = *(const bf16x8*)&Ps[w][row16][c * 32 + grp * 8];
            for (int dt = 0; dt < 4; dt++) {
                int d = dt * 16 + row16;
                int ck = cg ^ rm7 ^ ((dt * 2 + r3) & 7);
                bf16x8 vb = *(const bf16x8*)&VTs[d * 64 + ck * 8];
                o[dt] = __builtin_amdgcn_mfma_f32_16x16x32_bf16(pa, vb, o[dt], 0, 0, 0);
            }
        }
        __syncthreads();
    }

    // ---------------- Phase B: denominator-only tiles in [max(klo,qi+1), khi) ----------------
    {
        bf16x8 kf0[8], kf1[8];
        auto loadK = [&](int kk, bf16x8* kf) {
            const short* kt = Kp + base + (size_t)(kk * 64) * HD;
            for (int c = 0; c < 2; c++)
                for (int st = 0; st < 4; st++)
                    kf[c * 4 + st] = *(const bf16x8*)(kt + (size_t)(st * 16 + row16) * HD + c * 32 + grp * 8);
        };
        auto comp = [&](const bf16x8* kf) {
            f32x4 s[4];
            for (int st = 0; st < 4; st++) s[st] = (f32x4)0.f;
            for (int c = 0; c < 2; c++)
                for (int st = 0; st < 4; st++)
                    s[st] = __builtin_amdgcn_mfma_f32_16x16x32_bf16(q[c], kf[c * 4 + st], s[st], 0, 0, 0);
            for (int st = 0; st < 4; st++)
                for (int r = 0; r < 4; r++)
                    dsum[r] += __expf(s[st][r]);
        };
        int k = (qi + 1 > klo) ? qi + 1 : klo;
        if (k < khi) loadK(k, kf0);
        for (; k < khi; k += 2) {
            if (k + 1 < khi) loadK(k + 1, kf1);
            comp(kf0);
            if (k + 2 < khi) loadK(k + 2, kf0);
            if (k + 1 < khi) comp(kf1);
        }
    }

    // epilogue: partial denominator (reduced over 16 m-lanes) + partial o
    for (int r = 0; r < 4; r++) {
        float sum = dsum[r];
        sum += __shfl_xor(sum, 1, 64);
        sum += __shfl_xor(sum, 2, 64);
        sum += __shfl_xor(sum, 4, 64);
        sum += __shfl_xor(sum, 8, 64);
        int lq = qbase + grp * 4 + r;
        if (row16 == 0)
            part_d[((size_t)z * 32 + bh) * LSEQ + lq] = sum;
        for (int dt = 0; dt < 4; dt++)
            part_o[(((size_t)z * BSZ + b) * LSEQ + lq) * VECD + h * HD + dt * 16 + row16] = o[dt][r];
    }
}

// ---------------------------------------------------------------------------
// Kernel 3: combine partials + residual + LayerNorm (eps=1e-3), f32 output.
// One wave per row of 512. grid = 2048, block = 256.
// ---------------------------------------------------------------------------
__launch_bounds__(256)
__global__ void ln_kernel(const float* __restrict__ part_o, const float* __restrict__ part_d,
                          const float* __restrict__ q, const float* __restrict__ qmask,
                          const float* __restrict__ gamma, const float* __restrict__ beta,
                          float* __restrict__ out) {
    const int tid  = threadIdx.x;
    const int lane = tid & 63;
    const int w    = tid >> 6;
    const size_t row = (size_t)blockIdx.x * 4 + w;
    const int b = (int)(row >> 11);
    const int l = (int)(row & (LSEQ - 1));
    const int h = lane >> 3;          // head for this lane's 8 features
    const int bh = b * NH + h;

    const float* p0 = part_o + row * VECD + lane * 8;
    const float* p1 = p0 + (size_t)BSZ * LSEQ * VECD;
    float4 a0 = *(const float4*)p0;
    float4 a1 = *(const float4*)(p0 + 4);
    float4 c0 = *(const float4*)p1;
    float4 c1 = *(const float4*)(p1 + 4);

    float den = part_d[(size_t)bh * LSEQ + l] +
                part_d[(size_t)32 * LSEQ * 1 + (size_t)bh * LSEQ + l];
    float scale = qmask[b * LSEQ + l] / den;

    const float* qr = q + row * VECD + lane * 8;
    float4 b0 = *(const float4*)qr;
    float4 b1 = *(const float4*)(qr + 4);

    float y[8] = { (a0.x + c0.x) * scale + b0.x, (a0.y + c0.y) * scale + b0.y,
                   (a0.z + c0.z) * scale + b0.z, (a0.w + c0.w) * scale + b0.w,
                   (a1.x + c1.x) * scale + b1.x, (a1.y + c1.y) * scale + b1.y,
                   (a1.z + c1.z) * scale + b1.z, (a1.w + c1.w) * scale + b1.w };

    float s = 0.f;
    for (int j = 0; j < 8; j++) s += y[j];
    for (int off = 1; off < 64; off <<= 1) s += __shfl_xor(s, off, 64);
    float mean = s * (1.f / 512.f);

    float v = 0.f;
    for (int j = 0; j < 8; j++) { float d = y[j] - mean; v += d * d; }
    for (int off = 1; off < 64; off <<= 1) v += __shfl_xor(v, off, 64);
    float inv = rsqrtf(v * (1.f / 512.f) + 1e-3f);

    float4 g0 = *(const float4*)(gamma + lane * 8);
    float4 g1 = *(const float4*)(gamma + lane * 8 + 4);
    float4 e0 = *(const float4*)(beta + lane * 8);
    float4 e1 = *(const float4*)(beta + lane * 8 + 4);

    float4 o0, o1;
    o0.x = (y[0] - mean) * inv * g0.x + e0.x;
    o0.y = (y[1] - mean) * inv * g0.y + e0.y;
    o0.z = (y[2] - mean) * inv * g0.z + e0.z;
    o0.w = (y[3] - mean) * inv * g0.w + e0.w;
    o1.x = (y[4] - mean) * inv * g1.x + e1.x;
    o1.y = (y[5] - mean) * inv * g1.y + e1.y;
    o1.z = (y[6] - mean) * inv * g1.z + e1.z;
    o1.w = (y[7] - mean) * inv * g1.w + e1.w;
    *(float4*)(out + row * VECD + lane * 8) = o0;
    *(float4*)(out + row * VECD + lane * 8 + 4) = o1;
}

// ---------------------------------------------------------------------------
extern "C" void kernel_launch(void* const* d_in, const int* in_sizes, int n_in,
                              void* d_out, int out_size, void* d_ws, size_t ws_size,
                              hipStream_t stream) {
    const float* query = (const float*)d_in[0];
    const float* key   = (const float*)d_in[1];
    const float* value = (const float*)d_in[2];
    const float* qmask = (const float*)d_in[3];
    const float* vmask = (const float*)d_in[4];
    const float* Wq    = (const float*)d_in[5];
    const float* Wk    = (const float*)d_in[6];
    const float* Wv    = (const float*)d_in[7];
    const float* gamma = (const float*)d_in[8];
    const float* beta  = (const float*)d_in[9];

    // ws: Qp/Kp/Vp bf16 (8 MB each) | part_o f32 [2][B][L][512] (32 MB)
    //     | part_d f32 [2][32][L] (0.5 MB) | WT bf16 (1.5 MB)   -> ~58 MB
    const size_t QKV_ELTS = (size_t)BSZ * NH * LSEQ * HD;   // 4,194,304
    short* Qp = (short*)d_ws;
    short* Kp = Qp + QKV_ELTS;
    short* Vp = Kp + QKV_ELTS;
    float* part_o = (float*)(Vp + QKV_ELTS);
    float* part_d = part_o + (size_t)2 * BSZ * LSEQ * VECD;
    short* WT = (short*)(part_d + (size_t)2 * 32 * LSEQ);

    w_kernel<<<24, 256, 0, stream>>>(Wq, Wk, Wv, WT);
    proj_kernel<<<dim3(64, 4, 3), 256, 0, stream>>>(query, key, value, WT, Qp, Kp, Vp);
    attn_kernel<<<dim3(32, 32, 2), 256, 0, stream>>>(Qp, Kp, Vp, vmask, part_o, part_d);
    ln_kernel<<<2048, 256, 0, stream>>>(part_o, part_d, query, qmask, gamma, beta, (float*)d_out);
}

// Round 7
// 152.232 us; speedup vs baseline: 1.6653x; 1.6653x over previous
//
#include <hip/hip_runtime.h>
#include <hip/hip_bf16.h>

// Problem constants
#define BSZ 4
#define LSEQ 2048
#define VECD 512
#define NH 8
#define HD 64

typedef __attribute__((ext_vector_type(8))) short bf16x8;
typedef __attribute__((ext_vector_type(4))) short short4v;
typedef __attribute__((ext_vector_type(8))) short short8v;
typedef __attribute__((ext_vector_type(4))) float f32x4;

__device__ inline short f2bf(float f) {
    union { float f; unsigned u; } v; v.f = f;
    unsigned u = v.u;
    u += 0x7fffu + ((u >> 16) & 1u);   // RNE
    return (short)(u >> 16);
}

__device__ inline void gll16(const void* g, void* l) {
    __builtin_amdgcn_global_load_lds(
        (const __attribute__((address_space(1))) unsigned int*)g,
        (__attribute__((address_space(3))) unsigned int*)l, 16, 0, 0);
}

// ---------------------------------------------------------------------------
// Kernel 0: W -> WT bf16 transpose.  WT[z][(h*64+d)*512 + k] = W_z[h][k][d]
// ---------------------------------------------------------------------------
__launch_bounds__(256)
__global__ void w_kernel(const float* __restrict__ Wq, const float* __restrict__ Wk,
                         const float* __restrict__ Wv, short* __restrict__ WT) {
    __shared__ short T[64][72];
    const int bi = blockIdx.x;
    const int z = bi >> 3, h = bi & 7;
    const float* W = ((z == 0) ? Wq : (z == 1) ? Wk : Wv) + (size_t)h * VECD * HD;
    short* out = WT + (size_t)z * 512 * 512 + (size_t)h * 64 * 512;

    const int tid = threadIdx.x;
    for (int kt = 0; kt < 8; kt++) {
        int k0 = kt * 64;
        int r = tid >> 2, seg = tid & 3;
        for (int j = 0; j < 4; j++) {
            float4 v = *(const float4*)(W + (size_t)(k0 + r) * HD + seg * 16 + j * 4);
            T[seg * 16 + j * 4 + 0][r] = f2bf(v.x);
            T[seg * 16 + j * 4 + 1][r] = f2bf(v.y);
            T[seg * 16 + j * 4 + 2][r] = f2bf(v.z);
            T[seg * 16 + j * 4 + 3][r] = f2bf(v.w);
        }
        __syncthreads();
        int d = tid >> 2, ks = tid & 3;
        *(short8v*)(out + (size_t)d * 512 + k0 + ks * 16) = *(const short8v*)&T[d][ks * 16];
        *(short8v*)(out + (size_t)d * 512 + k0 + ks * 16 + 8) = *(const short8v*)&T[d][ks * 16 + 8];
        __syncthreads();
    }
}

// ---------------------------------------------------------------------------
// Kernel 1: QKV projection GEMM (unchanged from round 5).
// ---------------------------------------------------------------------------
__launch_bounds__(256, 3)
__global__ void proj_kernel(const float* __restrict__ q_in, const float* __restrict__ k_in,
                            const float* __restrict__ v_in, const short* __restrict__ WT,
                            short* __restrict__ Qp, short* __restrict__ Kp,
                            short* __restrict__ Vp) {
    __shared__ short As[128 * 64];
    __shared__ short Bs[128 * 64];

    const int z = blockIdx.z;
    const float* in = (z == 0) ? q_in : (z == 1) ? k_in : v_in;
    short* out      = (z == 0) ? Qp   : (z == 1) ? Kp   : Vp;
    const float sc  = (z == 0) ? 0.125f : 1.0f;
    const short* wt = WT + (size_t)z * 512 * 512;

    const int tid  = threadIdx.x;
    const int lane = tid & 63;
    const int w    = tid >> 6;
    const int r0   = blockIdx.x * 128;
    const int n0   = blockIdx.y * 128;

    const int row16 = lane & 15;
    const int grp   = lane >> 4;
    const int wm    = (w >> 1) * 64;
    const int wn    = (w & 1) * 64;

    f32x4 acc[4][4];
    for (int i = 0; i < 4; i++)
        for (int j = 0; j < 4; j++) acc[i][j] = (f32x4)0.f;

    for (int k0 = 0; k0 < VECD; k0 += 64) {
        for (int i = 0; i < 8; i++) {
            int id = tid + 256 * i;
            int m = id >> 4, kc4 = id & 15;
            float4 v = *(const float4*)(in + (size_t)(r0 + m) * VECD + k0 + kc4 * 4);
            int c = kc4 >> 1, half = kc4 & 1;
            short4v s4;
            s4[0] = f2bf(v.x); s4[1] = f2bf(v.y); s4[2] = f2bf(v.z); s4[3] = f2bf(v.w);
            *(short4v*)&As[m * 64 + (c ^ (m & 7)) * 8 + half * 4] = s4;
        }
        for (int i = 0; i < 4; i++) {
            int id = tid + 256 * i;
            int n = id >> 3, c = id & 7;
            gll16(wt + (size_t)(n0 + n) * 512 + k0 + ((c ^ (n & 7)) * 8),
                  (void*)(Bs + (w * 64 + 256 * i) * 8));
        }
        __syncthreads();

        for (int kc = 0; kc < 2; kc++) {
            bf16x8 a[4], b[4];
            for (int mt = 0; mt < 4; mt++) {
                int row = wm + mt * 16 + row16;
                int cg = kc * 4 + grp;
                a[mt] = *(const bf16x8*)&As[row * 64 + (cg ^ (row & 7)) * 8];
            }
            for (int nt = 0; nt < 4; nt++) {
                int row = wn + nt * 16 + row16;
                int cg = kc * 4 + grp;
                b[nt] = *(const bf16x8*)&Bs[row * 64 + (cg ^ (row & 7)) * 8];
            }
            for (int mt = 0; mt < 4; mt++)
                for (int nt = 0; nt < 4; nt++)
                    acc[mt][nt] = __builtin_amdgcn_mfma_f32_16x16x32_bf16(a[mt], b[nt], acc[mt][nt], 0, 0, 0);
        }
        __syncthreads();
    }

    for (int mt = 0; mt < 4; mt++)
        for (int r = 0; r < 4; r++) {
            int m = r0 + wm + mt * 16 + grp * 4 + r;
            int b = m >> 11, l = m & (LSEQ - 1);
            for (int nt = 0; nt < 4; nt++) {
                int n = n0 + wn + nt * 16 + row16;
                int h = n >> 6, d = n & 63;
                out[(((size_t)b * NH + h) * LSEQ + l) * HD + d] = f2bf(acc[mt][nt][r] * sc);
            }
        }
}

// ---------------------------------------------------------------------------
// Kernel 1b: V transpose.  VpT[bh][d][l] = Vp[bh][l][d].  grid (32, 32).
// ---------------------------------------------------------------------------
__launch_bounds__(256)
__global__ void vt_kernel(const short* __restrict__ Vp, short* __restrict__ VpT) {
    __shared__ short T[64][72];
    const int bh = blockIdx.y;
    const int l0 = blockIdx.x * 64;
    const short* src = Vp + (size_t)bh * LSEQ * HD + (size_t)l0 * HD;
    short* dst = VpT + (size_t)bh * HD * LSEQ;

    const int tid = threadIdx.x;
    const int row = tid >> 2, c16 = tid & 3;
    *(bf16x8*)&T[row][c16 * 16]     = *(const bf16x8*)(src + row * HD + c16 * 16);
    *(bf16x8*)&T[row][c16 * 16 + 8] = *(const bf16x8*)(src + row * HD + c16 * 16 + 8);
    __syncthreads();

    const int d = tid >> 2, seg = tid & 3;
    short8v o0, o1;
    for (int j = 0; j < 8; j++) o0[j] = T[seg * 16 + j][d];
    for (int j = 0; j < 8; j++) o1[j] = T[seg * 16 + 8 + j][d];
    *(short8v*)(dst + (size_t)d * LSEQ + l0 + seg * 16)     = o0;
    *(short8v*)(dst + (size_t)d * LSEQ + l0 + seg * 16 + 8) = o1;
}

// ---------------------------------------------------------------------------
// Kernel 2: attention (round-5 structure + T14 async-stage + VpT).
//  - phase A (k<=qi): K and V^T reg-staged; loads for tile t+1 issued during
//    tile t's compute; ds_write_b128 (swizzled) after the trailing barrier.
//  - phase B (k>qi): denominator only, K direct from global, reg dbuf.
// grid = (32, 32), block = 256 (4 waves, 16 q-rows each).
// ---------------------------------------------------------------------------
__launch_bounds__(256, 4)
__global__ void attn_kernel(const short* __restrict__ Qp, const short* __restrict__ Kp,
                            const short* __restrict__ VpT,
                            const float* __restrict__ qmask, const float* __restrict__ vmask,
                            float* __restrict__ x) {
    __shared__ short Ks[64 * 64];       // [m][k-chunks], slot c holds chunk c^(m&7)
    __shared__ short VTs[64 * 64];      // [d][m-chunks], slot c holds chunk c^(d&7)
    __shared__ short Ps[4][16][72];     // per-wave P: [q][m]

    const int tid  = threadIdx.x;
    const int lane = tid & 63;
    const int w    = tid >> 6;
    const int bh   = blockIdx.y;
    const int b    = bh >> 3;
    const int h    = bh & 7;
    // complementary-pair load-balance swizzle
    const int g    = (blockIdx.x + (bh & 15)) & 31;
    const int qi   = (bh & 16) ? (31 - g) : g;
    const int l0   = qi * 64;
    const int qbase = l0 + w * 16;
    const size_t base   = (size_t)bh * LSEQ * HD;
    const size_t vtbase = (size_t)bh * HD * LSEQ;

    const int row16 = lane & 15;
    const int grp   = lane >> 4;
    const int rm7   = row16 & 7;

    bf16x8 q[2];
    for (int c = 0; c < 2; c++)
        q[c] = *(const bf16x8*)(Qp + base + (size_t)(qbase + row16) * HD + c * 32 + grp * 8);

    f32x4 o[4];
    for (int i = 0; i < 4; i++) o[i] = (f32x4)0.f;
    float dsum[4] = {0.f, 0.f, 0.f, 0.f};

    // staging lambdas (K rows m, VpT rows d: identical index arithmetic)
    auto loadTile = [&](int k, bf16x8* sk, bf16x8* sv) {
        const int m0 = k * 64;
        const short* ksrc = Kp + base + (size_t)m0 * HD;
        for (int i = 0; i < 2; i++) {
            int id = tid + 256 * i;
            int m = id >> 3, c = id & 7;
            sk[i] = *(const bf16x8*)(ksrc + m * HD + ((c ^ (m & 7)) * 8));
            sv[i] = *(const bf16x8*)(VpT + vtbase + (size_t)m * LSEQ + m0 + ((c ^ (m & 7)) * 8));
        }
    };
    auto writeTile = [&](const bf16x8* sk, const bf16x8* sv) {
        for (int i = 0; i < 2; i++) {
            int id = tid + 256 * i;
            *(bf16x8*)&Ks[id * 8]  = sk[i];
            *(bf16x8*)&VTs[id * 8] = sv[i];
        }
    };

    // ---------------- Phase A: PV tiles k = 0..qi, T14 pipelined ----------------
    {
        bf16x8 k0f[2], v0f[2], k1f[2], v1f[2];
        loadTile(0, k0f, v0f);
        for (int k = 0; k <= qi; ++k) {
            if (k & 1) {
                writeTile(k1f, v1f);
                if (k < qi) loadTile(k + 1, k0f, v0f);
            } else {
                writeTile(k0f, v0f);
                if (k < qi) loadTile(k + 1, k1f, v1f);
            }
            __syncthreads();

            const int m0 = k * 64;
            f32x4 s[4];
            for (int st = 0; st < 4; st++) s[st] = (f32x4)0.f;
            for (int c = 0; c < 2; c++) {
                int ck = ((c << 2) | grp) ^ rm7;
                for (int st = 0; st < 4; st++) {
                    bf16x8 kf = *(const bf16x8*)&Ks[(st * 16 + row16) * 64 + ck * 8];
                    s[st] = __builtin_amdgcn_mfma_f32_16x16x32_bf16(q[c], kf, s[st], 0, 0, 0);
                }
            }

            float e[4][4];
            for (int st = 0; st < 4; st++)
                for (int r = 0; r < 4; r++) {
                    float ev = __expf(s[st][r]);
                    e[st][r] = ev;
                    dsum[r] += ev;
                }

            for (int st = 0; st < 4; st++) {
                int m = m0 + st * 16 + row16;
                float vm = vmask[b * LSEQ + m];
                for (int r = 0; r < 4; r++) {
                    int lq = qbase + grp * 4 + r;
                    float pv = (m <= lq) ? e[st][r] * vm : 0.f;
                    Ps[w][grp * 4 + r][st * 16 + row16] = f2bf(pv);
                }
            }

            for (int c = 0; c < 2; c++) {
                int ck = ((c << 2) | grp) ^ rm7;
                bf16x8 pa = *(const bf16x8*)&Ps[w][row16][c * 32 + grp * 8];
                for (int dt = 0; dt < 4; dt++) {
                    int d = dt * 16 + row16;
                    bf16x8 vb = *(const bf16x8*)&VTs[d * 64 + ck * 8];
                    o[dt] = __builtin_amdgcn_mfma_f32_16x16x32_bf16(pa, vb, o[dt], 0, 0, 0);
                }
            }
            __syncthreads();
        }
    }

    // ---------------- Phase B: denominator-only, reg double-buffered ----------------
    {
        bf16x8 kf0[8], kf1[8];
        auto loadK = [&](int kk, bf16x8* kf) {
            const short* kt = Kp + base + (size_t)(kk * 64) * HD;
            for (int c = 0; c < 2; c++)
                for (int st = 0; st < 4; st++)
                    kf[c * 4 + st] = *(const bf16x8*)(kt + (size_t)(st * 16 + row16) * HD + c * 32 + grp * 8);
        };
        auto comp = [&](const bf16x8* kf) {
            f32x4 s[4];
            for (int st = 0; st < 4; st++) s[st] = (f32x4)0.f;
            for (int c = 0; c < 2; c++)
                for (int st = 0; st < 4; st++)
                    s[st] = __builtin_amdgcn_mfma_f32_16x16x32_bf16(q[c], kf[c * 4 + st], s[st], 0, 0, 0);
            for (int st = 0; st < 4; st++)
                for (int r = 0; r < 4; r++)
                    dsum[r] += __expf(s[st][r]);
        };
        int k = qi + 1;
        if (k < 32) loadK(k, kf0);
        for (; k < 32; k += 2) {
            if (k + 1 < 32) loadK(k + 1, kf1);
            comp(kf0);
            if (k + 2 < 32) loadK(k + 2, kf0);
            if (k + 1 < 32) comp(kf1);
        }
    }

    // epilogue: reduce denominator over 16 m-lanes, apply query_mask, write x
    for (int r = 0; r < 4; r++) {
        float sum = dsum[r];
        sum += __shfl_xor(sum, 1, 64);
        sum += __shfl_xor(sum, 2, 64);
        sum += __shfl_xor(sum, 4, 64);
        sum += __shfl_xor(sum, 8, 64);
        int lq = qbase + grp * 4 + r;
        float inv = qmask[b * LSEQ + lq] / sum;
        for (int dt = 0; dt < 4; dt++)
            x[((size_t)b * LSEQ + lq) * VECD + h * HD + dt * 16 + row16] = o[dt][r] * inv;
    }
}

// ---------------------------------------------------------------------------
// Kernel 3: residual + LayerNorm (eps=1e-3), f32 output.
// ---------------------------------------------------------------------------
__launch_bounds__(256)
__global__ void ln_kernel(const float* __restrict__ x, const float* __restrict__ q,
                          const float* __restrict__ gamma, const float* __restrict__ beta,
                          float* __restrict__ out) {
    const int tid  = threadIdx.x;
    const int lane = tid & 63;
    const int w    = tid >> 6;
    const size_t row = (size_t)blockIdx.x * 4 + w;

    const float* xr = x + row * VECD + lane * 8;
    const float* qr = q + row * VECD + lane * 8;
    float4 a0 = *(const float4*)xr;
    float4 a1 = *(const float4*)(xr + 4);
    float4 b0 = *(const float4*)qr;
    float4 b1 = *(const float4*)(qr + 4);
    float y[8] = { a0.x + b0.x, a0.y + b0.y, a0.z + b0.z, a0.w + b0.w,
                   a1.x + b1.x, a1.y + b1.y, a1.z + b1.z, a1.w + b1.w };

    float s = 0.f;
    for (int j = 0; j < 8; j++) s += y[j];
    for (int off = 1; off < 64; off <<= 1) s += __shfl_xor(s, off, 64);
    float mean = s * (1.f / 512.f);

    float v = 0.f;
    for (int j = 0; j < 8; j++) { float d = y[j] - mean; v += d * d; }
    for (int off = 1; off < 64; off <<= 1) v += __shfl_xor(v, off, 64);
    float inv = rsqrtf(v * (1.f / 512.f) + 1e-3f);

    float4 g0 = *(const float4*)(gamma + lane * 8);
    float4 g1 = *(const float4*)(gamma + lane * 8 + 4);
    float4 e0 = *(const float4*)(beta + lane * 8);
    float4 e1 = *(const float4*)(beta + lane * 8 + 4);

    float4 o0, o1;
    o0.x = (y[0] - mean) * inv * g0.x + e0.x;
    o0.y = (y[1] - mean) * inv * g0.y + e0.y;
    o0.z = (y[2] - mean) * inv * g0.z + e0.z;
    o0.w = (y[3] - mean) * inv * g0.w + e0.w;
    o1.x = (y[4] - mean) * inv * g1.x + e1.x;
    o1.y = (y[5] - mean) * inv * g1.y + e1.y;
    o1.z = (y[6] - mean) * inv * g1.z + e1.z;
    o1.w = (y[7] - mean) * inv * g1.w + e1.w;
    *(float4*)(out + row * VECD + lane * 8) = o0;
    *(float4*)(out + row * VECD + lane * 8 + 4) = o1;
}

// ---------------------------------------------------------------------------
extern "C" void kernel_launch(void* const* d_in, const int* in_sizes, int n_in,
                              void* d_out, int out_size, void* d_ws, size_t ws_size,
                              hipStream_t stream) {
    const float* query = (const float*)d_in[0];
    const float* key   = (const float*)d_in[1];
    const float* value = (const float*)d_in[2];
    const float* qmask = (const float*)d_in[3];
    const float* vmask = (const float*)d_in[4];
    const float* Wq    = (const float*)d_in[5];
    const float* Wk    = (const float*)d_in[6];
    const float* Wv    = (const float*)d_in[7];
    const float* gamma = (const float*)d_in[8];
    const float* beta  = (const float*)d_in[9];

    // ws: Qp/Kp/Vp bf16 (8 MB each) | x f32 (16 MB) | WT bf16 (1.5 MB) | VpT bf16 (8 MB)
    const size_t QKV_ELTS = (size_t)BSZ * NH * LSEQ * HD;   // 4,194,304
    short* Qp = (short*)d_ws;
    short* Kp = Qp + QKV_ELTS;
    short* Vp = Kp + QKV_ELTS;
    float* x  = (float*)(Vp + QKV_ELTS);
    short* WT = (short*)(x + (size_t)BSZ * LSEQ * VECD);
    short* VpT = WT + (size_t)3 * 512 * 512;

    w_kernel<<<24, 256, 0, stream>>>(Wq, Wk, Wv, WT);
    proj_kernel<<<dim3(64, 4, 3), 256, 0, stream>>>(query, key, value, WT, Qp, Kp, Vp);
    vt_kernel<<<dim3(32, 32), 256, 0, stream>>>(Vp, VpT);
    attn_kernel<<<dim3(32, 32), 256, 0, stream>>>(Qp, Kp, VpT, qmask, vmask, x);
    ln_kernel<<<2048, 256, 0, stream>>>(x, query, gamma, beta, (float*)d_out);
}

// Round 8
// 126.234 us; speedup vs baseline: 2.0083x; 1.2059x over previous
//
#include <hip/hip_runtime.h>
#include <hip/hip_bf16.h>

// Problem constants
#define BSZ 4
#define LSEQ 2048
#define VECD 512
#define NH 8
#define HD 64

typedef __attribute__((ext_vector_type(8))) short bf16x8;
typedef __attribute__((ext_vector_type(4))) short short4v;
typedef __attribute__((ext_vector_type(8))) short short8v;
typedef __attribute__((ext_vector_type(4))) float f32x4;

__device__ inline short f2bf(float f) {
    union { float f; unsigned u; } v; v.f = f;
    unsigned u = v.u;
    u += 0x7fffu + ((u >> 16) & 1u);   // RNE
    return (short)(u >> 16);
}

__device__ inline unsigned cvtpk_bf16(float lo, float hi) {
    unsigned r;
    asm volatile("v_cvt_pk_bf16_f32 %0, %1, %2" : "=v"(r) : "v"(lo), "v"(hi));
    return r;
}

__device__ inline void gll16(const void* g, void* l) {
    __builtin_amdgcn_global_load_lds(
        (const __attribute__((address_space(1))) unsigned int*)g,
        (__attribute__((address_space(3))) unsigned int*)l, 16, 0, 0);
}

// ---------------------------------------------------------------------------
// Kernel 0: W -> WT bf16 transpose.  WT[z][(h*64+d)*512 + k] = W_z[h][k][d]
// ---------------------------------------------------------------------------
__launch_bounds__(256)
__global__ void w_kernel(const float* __restrict__ Wq, const float* __restrict__ Wk,
                         const float* __restrict__ Wv, short* __restrict__ WT) {
    __shared__ short T[64][72];
    const int bi = blockIdx.x;
    const int z = bi >> 3, h = bi & 7;
    const float* W = ((z == 0) ? Wq : (z == 1) ? Wk : Wv) + (size_t)h * VECD * HD;
    short* out = WT + (size_t)z * 512 * 512 + (size_t)h * 64 * 512;

    const int tid = threadIdx.x;
    for (int kt = 0; kt < 8; kt++) {
        int k0 = kt * 64;
        int r = tid >> 2, seg = tid & 3;
        for (int j = 0; j < 4; j++) {
            float4 v = *(const float4*)(W + (size_t)(k0 + r) * HD + seg * 16 + j * 4);
            T[seg * 16 + j * 4 + 0][r] = f2bf(v.x);
            T[seg * 16 + j * 4 + 1][r] = f2bf(v.y);
            T[seg * 16 + j * 4 + 2][r] = f2bf(v.z);
            T[seg * 16 + j * 4 + 3][r] = f2bf(v.w);
        }
        __syncthreads();
        int d = tid >> 2, ks = tid & 3;
        *(short8v*)(out + (size_t)d * 512 + k0 + ks * 16) = *(const short8v*)&T[d][ks * 16];
        *(short8v*)(out + (size_t)d * 512 + k0 + ks * 16 + 8) = *(const short8v*)&T[d][ks * 16 + 8];
        __syncthreads();
    }
}

// ---------------------------------------------------------------------------
// Kernel 1: QKV projection GEMM (unchanged).
// ---------------------------------------------------------------------------
__launch_bounds__(256, 3)
__global__ void proj_kernel(const float* __restrict__ q_in, const float* __restrict__ k_in,
                            const float* __restrict__ v_in, const short* __restrict__ WT,
                            short* __restrict__ Qp, short* __restrict__ Kp,
                            short* __restrict__ Vp) {
    __shared__ short As[128 * 64];
    __shared__ short Bs[128 * 64];

    const int z = blockIdx.z;
    const float* in = (z == 0) ? q_in : (z == 1) ? k_in : v_in;
    short* out      = (z == 0) ? Qp   : (z == 1) ? Kp   : Vp;
    const float sc  = (z == 0) ? 0.125f : 1.0f;
    const short* wt = WT + (size_t)z * 512 * 512;

    const int tid  = threadIdx.x;
    const int lane = tid & 63;
    const int w    = tid >> 6;
    const int r0   = blockIdx.x * 128;
    const int n0   = blockIdx.y * 128;

    const int row16 = lane & 15;
    const int grp   = lane >> 4;
    const int wm    = (w >> 1) * 64;
    const int wn    = (w & 1) * 64;

    f32x4 acc[4][4];
    for (int i = 0; i < 4; i++)
        for (int j = 0; j < 4; j++) acc[i][j] = (f32x4)0.f;

    for (int k0 = 0; k0 < VECD; k0 += 64) {
        for (int i = 0; i < 8; i++) {
            int id = tid + 256 * i;
            int m = id >> 4, kc4 = id & 15;
            float4 v = *(const float4*)(in + (size_t)(r0 + m) * VECD + k0 + kc4 * 4);
            int c = kc4 >> 1, half = kc4 & 1;
            short4v s4;
            s4[0] = f2bf(v.x); s4[1] = f2bf(v.y); s4[2] = f2bf(v.z); s4[3] = f2bf(v.w);
            *(short4v*)&As[m * 64 + (c ^ (m & 7)) * 8 + half * 4] = s4;
        }
        for (int i = 0; i < 4; i++) {
            int id = tid + 256 * i;
            int n = id >> 3, c = id & 7;
            gll16(wt + (size_t)(n0 + n) * 512 + k0 + ((c ^ (n & 7)) * 8),
                  (void*)(Bs + (w * 64 + 256 * i) * 8));
        }
        __syncthreads();

        for (int kc = 0; kc < 2; kc++) {
            bf16x8 a[4], b[4];
            for (int mt = 0; mt < 4; mt++) {
                int row = wm + mt * 16 + row16;
                int cg = kc * 4 + grp;
                a[mt] = *(const bf16x8*)&As[row * 64 + (cg ^ (row & 7)) * 8];
            }
            for (int nt = 0; nt < 4; nt++) {
                int row = wn + nt * 16 + row16;
                int cg = kc * 4 + grp;
                b[nt] = *(const bf16x8*)&Bs[row * 64 + (cg ^ (row & 7)) * 8];
            }
            for (int mt = 0; mt < 4; mt++)
                for (int nt = 0; nt < 4; nt++)
                    acc[mt][nt] = __builtin_amdgcn_mfma_f32_16x16x32_bf16(a[mt], b[nt], acc[mt][nt], 0, 0, 0);
        }
        __syncthreads();
    }

    for (int mt = 0; mt < 4; mt++)
        for (int r = 0; r < 4; r++) {
            int m = r0 + wm + mt * 16 + grp * 4 + r;
            int b = m >> 11, l = m & (LSEQ - 1);
            for (int nt = 0; nt < 4; nt++) {
                int n = n0 + wn + nt * 16 + row16;
                int h = n >> 6, d = n & 63;
                out[(((size_t)b * NH + h) * LSEQ + l) * HD + d] = f2bf(acc[mt][nt][r] * sc);
            }
        }
}

// ---------------------------------------------------------------------------
// Kernel 1b: V transpose.  VpT[bh][d][l] = Vp[bh][l][d].  grid (32, 32).
// ---------------------------------------------------------------------------
__launch_bounds__(256)
__global__ void vt_kernel(const short* __restrict__ Vp, short* __restrict__ VpT) {
    __shared__ short T[64][72];
    const int bh = blockIdx.y;
    const int l0 = blockIdx.x * 64;
    const short* src = Vp + (size_t)bh * LSEQ * HD + (size_t)l0 * HD;
    short* dst = VpT + (size_t)bh * HD * LSEQ;

    const int tid = threadIdx.x;
    const int row = tid >> 2, c16 = tid & 3;
    *(bf16x8*)&T[row][c16 * 16]     = *(const bf16x8*)(src + row * HD + c16 * 16);
    *(bf16x8*)&T[row][c16 * 16 + 8] = *(const bf16x8*)(src + row * HD + c16 * 16 + 8);
    __syncthreads();

    const int d = tid >> 2, seg = tid & 3;
    short8v o0, o1;
    for (int j = 0; j < 8; j++) o0[j] = T[seg * 16 + j][d];
    for (int j = 0; j < 8; j++) o1[j] = T[seg * 16 + 8 + j][d];
    *(short8v*)(dst + (size_t)d * LSEQ + l0 + seg * 16)     = o0;
    *(short8v*)(dst + (size_t)d * LSEQ + l0 + seg * 16 + 8) = o1;
}

// ---------------------------------------------------------------------------
// Kernel 2: attention, uniform paired-q-tile blocks.
// Block (x,bh) owns q-tiles tA=x (waves 0,1) and tB=63-x (waves 2,3), 32 rows
// each. Unified k=0..31 loop: K (and V for k<=kv) staged once; every wave does
// swapped QK^T + exp + denominator; waves with k <= kd(t) also do P.V via
// in-register cvt_pk P + per-wave Ps LDS. Per-block PV work = 33 tiles for
// every x -> perfectly uniform blocks. XCD swizzle: 4 bh per XCD (2MB in L2).
// grid = (32, 32), block = 256.
// ---------------------------------------------------------------------------
__launch_bounds__(256, 4)
__global__ void attn_kernel(const short* __restrict__ Qp, const short* __restrict__ Kp,
                            const short* __restrict__ VpT,
                            const float* __restrict__ qmask, const float* __restrict__ vmask,
                            float* __restrict__ x) {
    __shared__ short Ks[64 * 64];       // [m][k-chunks], slot c holds chunk c^(m&7)
    __shared__ short VTs[64 * 64];      // [d][m-chunks], slot c holds chunk c^(d&7)
    __shared__ short Ps[4][16][72];     // per-wave P^T: [q-row16][m-local]

    const int tid  = threadIdx.x;
    const int lane = tid & 63;
    const int w    = tid >> 6;

    // XCD-aware bijective swizzle: ii 0..1023 -> 4 bh per XCD
    const int ii  = blockIdx.x + 32 * blockIdx.y;
    const int swz = (ii & 7) * 128 + (ii >> 3);
    const int x31 = swz & 31;
    const int bh  = swz >> 5;
    const int b   = bh >> 3;
    const int h   = bh & 7;

    const int t   = (w < 2) ? x31 : (63 - x31);   // this wave's 32-row q-tile
    const int kd  = t >> 1;                        // last PV k-tile for this wave
    const int kv  = (63 - x31) >> 1;               // V-stage bound (max kd in block)
    const int qbase = t * 32 + (w & 1) * 16;

    const size_t base   = (size_t)bh * LSEQ * HD;
    const size_t vtbase = (size_t)bh * HD * LSEQ;

    const int row16 = lane & 15;
    const int grp   = lane >> 4;
    const int rm7   = row16 & 7;

    bf16x8 q[2];
    for (int c = 0; c < 2; c++)
        q[c] = *(const bf16x8*)(Qp + base + (size_t)(qbase + row16) * HD + c * 32 + grp * 8);

    f32x4 o[4];
    for (int i = 0; i < 4; i++) o[i] = (f32x4)0.f;
    float dsum = 0.f;

    // T14 reg-staging: K always, V only while k <= kv
    bf16x8 kra[2], krb[2], vra[2], vrb[2];
    auto loadTile = [&](int k, bf16x8* kr, bf16x8* vr) {
        const short* ksrc = Kp + base + (size_t)(k * 64) * HD;
        for (int i = 0; i < 2; i++) {
            int id = tid + 256 * i;
            int m = id >> 3, c = id & 7;
            kr[i] = *(const bf16x8*)(ksrc + m * HD + ((c ^ (m & 7)) * 8));
            if (k <= kv)
                vr[i] = *(const bf16x8*)(VpT + vtbase + (size_t)m * LSEQ + k * 64 + ((c ^ (m & 7)) * 8));
        }
    };
    auto writeTile = [&](int k, const bf16x8* kr, const bf16x8* vr) {
        for (int i = 0; i < 2; i++) {
            int id = tid + 256 * i;
            *(bf16x8*)&Ks[id * 8] = kr[i];
            if (k <= kv) *(bf16x8*)&VTs[id * 8] = vr[i];
        }
    };

    loadTile(0, kra, vra);
    writeTile(0, kra, vra);

    for (int k = 0; k < 32; ++k) {
        __syncthreads();   // tile k staged for all

        // issue next tile's global loads early (hide under compute)
        bf16x8* krn = (k & 1) ? kra : krb;
        bf16x8* vrn = (k & 1) ? vra : vrb;
        if (k < 31) loadTile(k + 1, krn, vrn);

        // swapped QK^T: s[st][r] = S[q=qbase+row16][m = k*64 + st*16 + grp*4 + r]
        f32x4 s[4];
        for (int st = 0; st < 4; st++) s[st] = (f32x4)0.f;
        for (int c = 0; c < 2; c++) {
            int ck = ((c << 2) | grp) ^ rm7;
            for (int st = 0; st < 4; st++) {
                bf16x8 kf = *(const bf16x8*)&Ks[(st * 16 + row16) * 64 + ck * 8];
                s[st] = __builtin_amdgcn_mfma_f32_16x16x32_bf16(kf, q[c], s[st], 0, 0, 0);
            }
        }

        // exp + full-row denominator (all waves, all k)
        float ev[4][4];
        for (int st = 0; st < 4; st++)
            for (int r = 0; r < 4; r++) {
                float e = __expf(s[st][r]);
                ev[st][r] = e;
                dsum += e;
            }

        if (k <= kd) {
            // vmask (+ causal only on the diagonal tile), pack to bf16, P^T -> Ps
            for (int st = 0; st < 4; st++) {
                float4 vm4 = *(const float4*)(vmask + b * LSEQ + k * 64 + st * 16 + grp * 4);
                float pv0 = ev[st][0] * vm4.x, pv1 = ev[st][1] * vm4.y;
                float pv2 = ev[st][2] * vm4.z, pv3 = ev[st][3] * vm4.w;
                if (k == kd) {
                    int mb = k * 64 + st * 16 + grp * 4, lq = qbase + row16;
                    pv0 = (mb + 0 <= lq) ? pv0 : 0.f;
                    pv1 = (mb + 1 <= lq) ? pv1 : 0.f;
                    pv2 = (mb + 2 <= lq) ? pv2 : 0.f;
                    pv3 = (mb + 3 <= lq) ? pv3 : 0.f;
                }
                unsigned p01 = cvtpk_bf16(pv0, pv1);
                unsigned p23 = cvtpk_bf16(pv2, pv3);
                uint2 pk; pk.x = p01; pk.y = p23;
                *(uint2*)&Ps[w][row16][st * 16 + grp * 4] = pk;
            }

            // PV: pa = P^T row (contiguous), vb from swizzled VTs
            for (int c = 0; c < 2; c++) {
                bf16x8 pa = *(const bf16x8*)&Ps[w][row16][c * 32 + grp * 8];
                int ck = ((c << 2) | grp) ^ rm7;
                for (int dt = 0; dt < 4; dt++) {
                    int d = dt * 16 + row16;
                    bf16x8 vb = *(const bf16x8*)&VTs[d * 64 + ck * 8];
                    o[dt] = __builtin_amdgcn_mfma_f32_16x16x32_bf16(pa, vb, o[dt], 0, 0, 0);
                }
            }
        }

        __syncthreads();   // everyone done reading tile k
        if (k < 31) writeTile(k + 1, krn, vrn);
    }

    // denominator: reduce over the 4 grp copies (m-partition), then fetch per-q
    dsum += __shfl_xor(dsum, 16, 64);
    dsum += __shfl_xor(dsum, 32, 64);

    for (int r = 0; r < 4; r++) {
        int lq = qbase + grp * 4 + r;
        float den = __shfl(dsum, grp * 4 + r, 64);
        float inv = qmask[b * LSEQ + lq] / den;
        for (int dt = 0; dt < 4; dt++)
            x[((size_t)b * LSEQ + lq) * VECD + h * HD + dt * 16 + row16] = o[dt][r] * inv;
    }
}

// ---------------------------------------------------------------------------
// Kernel 3: residual + LayerNorm (eps=1e-3), f32 output.
// ---------------------------------------------------------------------------
__launch_bounds__(256)
__global__ void ln_kernel(const float* __restrict__ x, const float* __restrict__ q,
                          const float* __restrict__ gamma, const float* __restrict__ beta,
                          float* __restrict__ out) {
    const int tid  = threadIdx.x;
    const int lane = tid & 63;
    const int w    = tid >> 6;
    const size_t row = (size_t)blockIdx.x * 4 + w;

    const float* xr = x + row * VECD + lane * 8;
    const float* qr = q + row * VECD + lane * 8;
    float4 a0 = *(const float4*)xr;
    float4 a1 = *(const float4*)(xr + 4);
    float4 b0 = *(const float4*)qr;
    float4 b1 = *(const float4*)(qr + 4);
    float y[8] = { a0.x + b0.x, a0.y + b0.y, a0.z + b0.z, a0.w + b0.w,
                   a1.x + b1.x, a1.y + b1.y, a1.z + b1.z, a1.w + b1.w };

    float s = 0.f;
    for (int j = 0; j < 8; j++) s += y[j];
    for (int off = 1; off < 64; off <<= 1) s += __shfl_xor(s, off, 64);
    float mean = s * (1.f / 512.f);

    float v = 0.f;
    for (int j = 0; j < 8; j++) { float d = y[j] - mean; v += d * d; }
    for (int off = 1; off < 64; off <<= 1) v += __shfl_xor(v, off, 64);
    float inv = rsqrtf(v * (1.f / 512.f) + 1e-3f);

    float4 g0 = *(const float4*)(gamma + lane * 8);
    float4 g1 = *(const float4*)(gamma + lane * 8 + 4);
    float4 e0 = *(const float4*)(beta + lane * 8);
    float4 e1 = *(const float4*)(beta + lane * 8 + 4);

    float4 o0, o1;
    o0.x = (y[0] - mean) * inv * g0.x + e0.x;
    o0.y = (y[1] - mean) * inv * g0.y + e0.y;
    o0.z = (y[2] - mean) * inv * g0.z + e0.z;
    o0.w = (y[3] - mean) * inv * g0.w + e0.w;
    o1.x = (y[4] - mean) * inv * g1.x + e1.x;
    o1.y = (y[5] - mean) * inv * g1.y + e1.y;
    o1.z = (y[6] - mean) * inv * g1.z + e1.z;
    o1.w = (y[7] - mean) * inv * g1.w + e1.w;
    *(float4*)(out + row * VECD + lane * 8) = o0;
    *(float4*)(out + row * VECD + lane * 8 + 4) = o1;
}

// ---------------------------------------------------------------------------
extern "C" void kernel_launch(void* const* d_in, const int* in_sizes, int n_in,
                              void* d_out, int out_size, void* d_ws, size_t ws_size,
                              hipStream_t stream) {
    const float* query = (const float*)d_in[0];
    const float* key   = (const float*)d_in[1];
    const float* value = (const float*)d_in[2];
    const float* qmask = (const float*)d_in[3];
    const float* vmask = (const float*)d_in[4];
    const float* Wq    = (const float*)d_in[5];
    const float* Wk    = (const float*)d_in[6];
    const float* Wv    = (const float*)d_in[7];
    const float* gamma = (const float*)d_in[8];
    const float* beta  = (const float*)d_in[9];

    // ws: Qp/Kp/Vp bf16 (8 MB each) | x f32 (16 MB) | WT bf16 (1.5 MB) | VpT bf16 (8 MB)
    const size_t QKV_ELTS = (size_t)BSZ * NH * LSEQ * HD;   // 4,194,304
    short* Qp = (short*)d_ws;
    short* Kp = Qp + QKV_ELTS;
    short* Vp = Kp + QKV_ELTS;
    float* x  = (float*)(Vp + QKV_ELTS);
    short* WT = (short*)(x + (size_t)BSZ * LSEQ * VECD);
    short* VpT = WT + (size_t)3 * 512 * 512;

    w_kernel<<<24, 256, 0, stream>>>(Wq, Wk, Wv, WT);
    proj_kernel<<<dim3(64, 4, 3), 256, 0, stream>>>(query, key, value, WT, Qp, Kp, Vp);
    vt_kernel<<<dim3(32, 32), 256, 0, stream>>>(Vp, VpT);
    attn_kernel<<<dim3(32, 32), 256, 0, stream>>>(Qp, Kp, VpT, qmask, vmask, x);
    ln_kernel<<<2048, 256, 0, stream>>>(x, query, gamma, beta, (float*)d_out);
}